// Round 1
// baseline (285.656 us; speedup 1.0000x reference)
//
#include <hip/hip_runtime.h>
#include <stdint.h>

#define BLOCK 256
#define ITEMS 8
#define TILE (BLOCK * ITEMS)
#define MAXSEG 64
#define THRESH 0.1f

__device__ __forceinline__ int find_seg(const int* rs, int n_seg, int i) {
    // largest s with rs[s] <= i ; invariant rs[lo] <= i < rs[hi]
    int lo = 0, hi = n_seg;
    while (hi - lo > 1) {
        int mid = (lo + hi) >> 1;
        if (rs[mid] <= i) lo = mid; else hi = mid;
    }
    return lo;
}

__global__ void k_init(unsigned int* seg_min_bits, int* first_min_idx, int n_seg) {
    int t = blockIdx.x * blockDim.x + threadIdx.x;
    if (t < n_seg) {
        seg_min_bits[t] = 0x7F800000u;   // +inf bits
        first_min_idx[t] = 0x7FFFFFFF;
    }
}

// Pass 1: per-segment min (scores >= 0 so uint-bit order == float order)
__global__ __launch_bounds__(BLOCK) void k_min(const float* __restrict__ score,
        const int* __restrict__ row_splits, int n_seg, int n,
        unsigned int* __restrict__ seg_min_bits) {
    __shared__ int rs[MAXSEG + 1];
    __shared__ unsigned int lmin[MAXSEG + 1];
    for (int j = threadIdx.x; j <= n_seg; j += BLOCK) rs[j] = row_splits[j];
    __syncthreads();
    int base = blockIdx.x * TILE;
    int endi = min(n, base + TILE);
    int seg_lo = find_seg(rs, n_seg, base);
    int seg_hi = find_seg(rs, n_seg, endi - 1);
    int span = seg_hi - seg_lo;
    for (int j = threadIdx.x; j <= span; j += BLOCK) lmin[j] = 0xFFFFFFFFu;
    __syncthreads();

    int tbase = base + threadIdx.x * ITEMS;
    if (tbase < n) {
        float v[ITEMS];
        if (tbase + ITEMS <= n) {
            float4 f0 = *(const float4*)(score + tbase);
            float4 f1 = *(const float4*)(score + tbase + 4);
            v[0]=f0.x; v[1]=f0.y; v[2]=f0.z; v[3]=f0.w;
            v[4]=f1.x; v[5]=f1.y; v[6]=f1.z; v[7]=f1.w;
        } else {
            for (int j = 0; j < ITEMS; j++) v[j] = (tbase + j < n) ? score[tbase + j] : 1.0f;
        }
        int seg = seg_lo;
        while (seg < seg_hi && rs[seg + 1] <= tbase) seg++;
        unsigned int cur = 0xFFFFFFFFu;
        int curseg = seg;
        #pragma unroll
        for (int j = 0; j < ITEMS; j++) {
            int i = tbase + j;
            if (i >= n) break;
            while (seg < seg_hi && rs[seg + 1] <= i) seg++;
            if (seg != curseg) {
                atomicMin(&lmin[curseg - seg_lo], cur);
                cur = 0xFFFFFFFFu; curseg = seg;
            }
            unsigned int b = __float_as_uint(v[j]);
            cur = min(cur, b);
        }
        atomicMin(&lmin[curseg - seg_lo], cur);
    }
    __syncthreads();
    for (int j = threadIdx.x; j <= span; j += BLOCK)
        if (lmin[j] != 0xFFFFFFFFu)
            atomicMin(&seg_min_bits[seg_lo + j], lmin[j]);
}

// Pass 2: per-block keep count + first (index-min) segment-min element
__global__ __launch_bounds__(BLOCK) void k_count(const float* __restrict__ score,
        const int* __restrict__ row_splits, int n_seg, int n,
        const unsigned int* __restrict__ seg_min_bits,
        int* __restrict__ first_min_idx,
        int* __restrict__ block_counts) {
    __shared__ int rs[MAXSEG + 1];
    __shared__ unsigned int smin[MAXSEG];
    __shared__ int wsum[BLOCK / 64];
    for (int j = threadIdx.x; j <= n_seg; j += BLOCK) rs[j] = row_splits[j];
    for (int j = threadIdx.x; j < n_seg; j += BLOCK) smin[j] = seg_min_bits[j];
    __syncthreads();
    int base = blockIdx.x * TILE;
    int seg_lo = find_seg(rs, n_seg, base);
    int tbase = base + threadIdx.x * ITEMS;
    int c = 0;
    if (tbase < n) {
        float v[ITEMS];
        if (tbase + ITEMS <= n) {
            float4 f0 = *(const float4*)(score + tbase);
            float4 f1 = *(const float4*)(score + tbase + 4);
            v[0]=f0.x; v[1]=f0.y; v[2]=f0.z; v[3]=f0.w;
            v[4]=f1.x; v[5]=f1.y; v[6]=f1.z; v[7]=f1.w;
        } else {
            for (int j = 0; j < ITEMS; j++) v[j] = (tbase + j < n) ? score[tbase + j] : 1.0f;
        }
        int seg = seg_lo;
        while (seg < n_seg - 1 && rs[seg + 1] <= tbase) seg++;
        #pragma unroll
        for (int j = 0; j < ITEMS; j++) {
            int i = tbase + j;
            if (i >= n) break;
            while (seg < n_seg - 1 && rs[seg + 1] <= i) seg++;
            unsigned int b = __float_as_uint(v[j]);
            bool ismin = (b == smin[seg]);
            bool keep = (v[j] > THRESH) || ismin;
            c += keep ? 1 : 0;
            if (ismin) atomicMin(&first_min_idx[seg], i);  // rare
        }
    }
    int lane = threadIdx.x & 63, w = threadIdx.x >> 6;
    int s = c;
    for (int o = 32; o > 0; o >>= 1) s += __shfl_down(s, o, 64);
    if (lane == 0) wsum[w] = s;
    __syncthreads();
    if (threadIdx.x == 0) {
        int t = 0;
        for (int k = 0; k < BLOCK / 64; k++) t += wsum[k];
        block_counts[blockIdx.x] = t;
    }
}

// Pass 3: single-block exclusive scan of block counts
__global__ __launch_bounds__(BLOCK) void k_scan(const int* __restrict__ counts,
                                                int* __restrict__ offsets, int nb) {
    __shared__ int lds[BLOCK];
    __shared__ int running;
    if (threadIdx.x == 0) running = 0;
    __syncthreads();
    for (int start = 0; start < nb; start += BLOCK) {
        int i = start + threadIdx.x;
        int v = (i < nb) ? counts[i] : 0;
        lds[threadIdx.x] = v;
        __syncthreads();
        for (int o = 1; o < BLOCK; o <<= 1) {
            int t = (threadIdx.x >= o) ? lds[threadIdx.x - o] : 0;
            __syncthreads();
            lds[threadIdx.x] += t;
            __syncthreads();
        }
        int incl = lds[threadIdx.x];
        int base = running;
        if (i < nb) offsets[i] = base + incl - v;
        __syncthreads();
        if (threadIdx.x == BLOCK - 1) running = base + incl;
        __syncthreads();
    }
}

// Pass 4: exclusive kept-count at arbitrary indices -> newrs + rep_pos.
// One wave per query (129 queries), lanes cooperate over <= TILE elements.
__global__ __launch_bounds__(BLOCK) void k_query(const float* __restrict__ score,
        const int* __restrict__ row_splits, int n_seg, int n, int M,
        const unsigned int* __restrict__ seg_min_bits,
        const int* __restrict__ first_min_idx,
        const int* __restrict__ block_offsets,
        int* __restrict__ rep_pos, int* __restrict__ newrs_out) {
    __shared__ int rs[MAXSEG + 1];
    __shared__ unsigned int smin[MAXSEG];
    for (int j = threadIdx.x; j <= n_seg; j += BLOCK) rs[j] = row_splits[j];
    for (int j = threadIdx.x; j < n_seg; j += BLOCK) smin[j] = seg_min_bits[j];
    __syncthreads();
    int wv = threadIdx.x >> 6, lane = threadIdx.x & 63;
    int q = blockIdx.x * (BLOCK / 64) + wv;
    int nq = 2 * n_seg + 1;
    if (q >= nq) return;
    int idx = (q <= n_seg) ? rs[q] : first_min_idx[q - (n_seg + 1)];
    int result;
    if (idx >= n) {
        result = M;
    } else {
        int b = idx / TILE;
        int startb = b * TILE;
        int cnt = 0;
        for (int i = startb + lane; i < idx; i += 64) {
            float v = score[i];
            unsigned int bts = __float_as_uint(v);
            int seg = find_seg(rs, n_seg, i);
            if ((v > THRESH) || (bts == smin[seg])) cnt++;
        }
        for (int o = 32; o > 0; o >>= 1) cnt += __shfl_down(cnt, o, 64);
        result = block_offsets[b] + cnt;   // lane 0 holds full sum
    }
    if (lane == 0) {
        if (q <= n_seg) newrs_out[q] = result;
        else rep_pos[q - (n_seg + 1)] = result;
    }
}

// Pass 5: final outputs: sel (scatter) + backgather
__global__ __launch_bounds__(BLOCK) void k_output(const float* __restrict__ score,
        const int* __restrict__ row_splits, int n_seg, int n,
        const unsigned int* __restrict__ seg_min_bits,
        const int* __restrict__ rep_pos,
        const int* __restrict__ block_offsets,
        int* __restrict__ sel_out, int* __restrict__ back_out) {
    __shared__ int rs[MAXSEG + 1];
    __shared__ unsigned int smin[MAXSEG];
    __shared__ int srep[MAXSEG];
    __shared__ int wsum[BLOCK / 64];
    for (int j = threadIdx.x; j <= n_seg; j += BLOCK) rs[j] = row_splits[j];
    for (int j = threadIdx.x; j < n_seg; j += BLOCK) {
        smin[j] = seg_min_bits[j];
        srep[j] = rep_pos[j];
    }
    __syncthreads();
    int base = blockIdx.x * TILE;
    int seg_lo = find_seg(rs, n_seg, base);
    int tbase = base + threadIdx.x * ITEMS;
    float v[ITEMS];
    bool keepf[ITEMS];
    int c = 0;
    int seg0 = seg_lo;
    if (tbase < n) {
        if (tbase + ITEMS <= n) {
            float4 f0 = *(const float4*)(score + tbase);
            float4 f1 = *(const float4*)(score + tbase + 4);
            v[0]=f0.x; v[1]=f0.y; v[2]=f0.z; v[3]=f0.w;
            v[4]=f1.x; v[5]=f1.y; v[6]=f1.z; v[7]=f1.w;
        } else {
            for (int j = 0; j < ITEMS; j++) v[j] = (tbase + j < n) ? score[tbase + j] : 1.0f;
        }
        int seg = seg_lo;
        while (seg < n_seg - 1 && rs[seg + 1] <= tbase) seg++;
        seg0 = seg;
        #pragma unroll
        for (int j = 0; j < ITEMS; j++) {
            int i = tbase + j;
            if (i >= n) { keepf[j] = false; continue; }
            while (seg < n_seg - 1 && rs[seg + 1] <= i) seg++;
            unsigned int b = __float_as_uint(v[j]);
            keepf[j] = (v[j] > THRESH) || (b == smin[seg]);
            c += keepf[j] ? 1 : 0;
        }
    } else {
        for (int j = 0; j < ITEMS; j++) keepf[j] = false;
    }
    // block exclusive scan of per-thread counts
    int lane = threadIdx.x & 63, w = threadIdx.x >> 6;
    int incl = c;
    for (int o = 1; o < 64; o <<= 1) {
        int t = __shfl_up(incl, o, 64);
        if (lane >= o) incl += t;
    }
    if (lane == 63) wsum[w] = incl;
    __syncthreads();
    int excl = incl - c;
    for (int k = 0; k < w; k++) excl += wsum[k];
    int kp = block_offsets[blockIdx.x] + excl;

    if (tbase < n) {
        int bg[ITEMS];
        int seg = seg0;
        #pragma unroll
        for (int j = 0; j < ITEMS; j++) {
            int i = tbase + j;
            if (i >= n) { bg[j] = 0; continue; }
            while (seg < n_seg - 1 && rs[seg + 1] <= i) seg++;
            if (keepf[j]) {
                bg[j] = kp;
                sel_out[kp] = i;
                kp++;
            } else {
                bg[j] = srep[seg];
            }
        }
        if (tbase + ITEMS <= n && ((((uintptr_t)(back_out + tbase)) & 15) == 0)) {
            int4 o0 = make_int4(bg[0], bg[1], bg[2], bg[3]);
            int4 o1 = make_int4(bg[4], bg[5], bg[6], bg[7]);
            *(int4*)(back_out + tbase) = o0;
            *(int4*)(back_out + tbase + 4) = o1;
        } else {
            for (int j = 0; j < ITEMS && tbase + j < n; j++) back_out[tbase + j] = bg[j];
        }
    }
}

extern "C" void kernel_launch(void* const* d_in, const int* in_sizes, int n_in,
                              void* d_out, int out_size, void* d_ws, size_t ws_size,
                              hipStream_t stream) {
    const float* score = (const float*)d_in[0];
    const int* row_splits = (const int*)d_in[1];
    int n = in_sizes[0];
    int n_seg = in_sizes[1] - 1;
    int M = out_size - (n_seg + 1) - n;   // kept count, from harness-known out_size
    int nb = (n + TILE - 1) / TILE;

    unsigned int* seg_min_bits = (unsigned int*)d_ws;
    int* first_min_idx = (int*)d_ws + 64;
    int* rep_pos       = (int*)d_ws + 128;
    int* block_counts  = (int*)d_ws + 192;
    int* block_offsets = block_counts + nb;

    int* out = (int*)d_out;
    int* sel_out   = out;
    int* newrs_out = out + M;
    int* back_out  = out + M + (n_seg + 1);

    hipLaunchKernelGGL(k_init, dim3(1), dim3(64), 0, stream,
                       seg_min_bits, first_min_idx, n_seg);
    hipLaunchKernelGGL(k_min, dim3(nb), dim3(BLOCK), 0, stream,
                       score, row_splits, n_seg, n, seg_min_bits);
    hipLaunchKernelGGL(k_count, dim3(nb), dim3(BLOCK), 0, stream,
                       score, row_splits, n_seg, n, seg_min_bits, first_min_idx, block_counts);
    hipLaunchKernelGGL(k_scan, dim3(1), dim3(BLOCK), 0, stream,
                       block_counts, block_offsets, nb);
    int nq = 2 * n_seg + 1;
    int qblocks = (nq + (BLOCK / 64) - 1) / (BLOCK / 64);
    hipLaunchKernelGGL(k_query, dim3(qblocks), dim3(BLOCK), 0, stream,
                       score, row_splits, n_seg, n, M, seg_min_bits, first_min_idx,
                       block_offsets, rep_pos, newrs_out);
    hipLaunchKernelGGL(k_output, dim3(nb), dim3(BLOCK), 0, stream,
                       score, row_splits, n_seg, n, seg_min_bits, rep_pos,
                       block_offsets, sel_out, back_out);
}